// Round 7
// baseline (198.424 us; speedup 1.0000x reference)
//
#include <hip/hip_runtime.h>

// DCT_18769007084406: RGB->YCbCr (1x1 conv) -> 8x8 stride-8 block DCT
// (grouped conv) -> 32x repeated (t-min)/d normalization (closed form).
//
// R7: barrier-free register pipeline. No LDS, no __syncthreads -> no
// s_waitcnt vmcnt(0) drains anywhere. Persistent block = (b, by-pair),
// 192 threads (3 waves = 3 YCbCr channels, lane = block-col). Rows are
// streamed with a depth-2 register prefetch (rb[2][6] float4): consume
// row r, immediately issue loads for row r+2 (crosses the band seam, so
// the 64-store epilogue of band 0 overlaps band 1's first row loads).
// Each wave keeps ~12KB of loads continuously in flight; stores are
// never waited on. Compiler inserts only fine-grained per-use vmcnt.

#define HW 512
#define CHST (HW * HW)       // channel stride in x (floats)
#define NPAIR 6144           // 32 * 192 (b, out-channel) pairs
#define EPS 1e-6f

// basis[u][i] = c(u) * cos(pi*u*(i+0.5)/8); c(0)=sqrt(1/8), c(u>0)=0.5
static constexpr float BASIS[8][8] = {
  { 0.35355339059327373f, 0.35355339059327373f, 0.35355339059327373f, 0.35355339059327373f,
    0.35355339059327373f, 0.35355339059327373f, 0.35355339059327373f, 0.35355339059327373f },
  { 0.49039264020161522f, 0.41573480615127262f, 0.27778511650980114f, 0.09754516100806412f,
   -0.09754516100806412f,-0.27778511650980114f,-0.41573480615127262f,-0.49039264020161522f },
  { 0.46193976625564337f, 0.19134171618254492f,-0.19134171618254492f,-0.46193976625564337f,
   -0.46193976625564337f,-0.19134171618254492f, 0.19134171618254492f, 0.46193976625564337f },
  { 0.41573480615127262f,-0.09754516100806412f,-0.49039264020161522f,-0.27778511650980114f,
    0.27778511650980114f, 0.49039264020161522f, 0.09754516100806412f,-0.41573480615127262f },
  { 0.35355339059327373f,-0.35355339059327373f,-0.35355339059327373f, 0.35355339059327373f,
    0.35355339059327373f,-0.35355339059327373f,-0.35355339059327373f, 0.35355339059327373f },
  { 0.27778511650980114f,-0.49039264020161522f, 0.09754516100806412f, 0.41573480615127262f,
   -0.41573480615127262f,-0.09754516100806412f, 0.49039264020161522f,-0.27778511650980114f },
  { 0.19134171618254492f,-0.46193976625564337f, 0.46193976625564337f,-0.19134171618254492f,
   -0.19134171618254492f, 0.46193976625564337f,-0.46193976625564337f, 0.19134171618254492f },
  { 0.09754516100806412f,-0.27778511650980114f, 0.41573480615127262f,-0.49039264020161522f,
    0.49039264020161522f,-0.41573480615127262f, 0.27778511650980114f,-0.09754516100806412f }
};

// t_32 = a^32 * t0 - min * sum_{k=1..32} a^k, a = 1/(max-min+eps)
__global__ void precomp_norm(const float* __restrict__ max_,
                             const float* __restrict__ min_,
                             float* __restrict__ so) {
    int i = blockIdx.x * 256 + threadIdx.x;
    if (i >= NPAIR) return;
    float mn = min_[i], mx = max_[i];
    float d = mx - mn + EPS;
    float a = 1.0f / d;
    float a2 = a * a, a4 = a2 * a2, a8 = a4 * a4, a16 = a8 * a8, a32 = a16 * a16;
    float geo = a * (1.0f - a32) / (1.0f - a);   // sum_{k=1..32} a^k
    so[2 * i]     = a32;
    so[2 * i + 1] = -mn * geo;
}

template <bool USE_WS>
__global__ __launch_bounds__(192)
void dct_kernel(const float* __restrict__ x,
                const float* __restrict__ ycbcr_w,
                const float* __restrict__ so,
                const float* __restrict__ max_,
                const float* __restrict__ min_,
                float* __restrict__ out) {
    const int g    = blockIdx.x;
    const int b    = g >> 5;             // batch (32)
    const int byp  = g & 31;             // by-pair: bands by = 2*byp, 2*byp+1
    const int c    = threadIdx.x >> 6;   // wave = YCbCr channel
    const int bx   = threadIdx.x & 63;   // lane = block-col (coalesced I/O)

    const float w0 = ycbcr_w[c * 3 + 0];
    const float w1 = ycbcr_w[c * 3 + 1];
    const float w2 = ycbcr_w[c * 3 + 2];

    // rows r = 0..15 cover the 2 bands; global row = byp*16 + r
    const float* xb = x + (size_t)(b * 3) * CHST + (size_t)(byp * 16) * HW + bx * 8;

    float4 rb[2][6];   // depth-2 row prefetch: [slot][ch0 lo,hi, ch1 lo,hi, ch2 lo,hi]

    auto issue = [&](int slot, int r) {
        const float* p = xb + (size_t)r * HW;
        rb[slot][0] = *(const float4*)(p);
        rb[slot][1] = *(const float4*)(p + 4);
        rb[slot][2] = *(const float4*)(p + CHST);
        rb[slot][3] = *(const float4*)(p + CHST + 4);
        rb[slot][4] = *(const float4*)(p + 2 * CHST);
        rb[slot][5] = *(const float4*)(p + 2 * CHST + 4);
    };

    issue(0, 0);
    issue(1, 1);

    const int obase = b * 192 + c * 64;  // first output channel (b, o)

    float tmp[8][8];
#pragma unroll
    for (int u = 0; u < 8; ++u)
#pragma unroll
        for (int j = 0; j < 8; ++j) tmp[u][j] = 0.0f;

#pragma unroll
    for (int r = 0; r < 16; ++r) {
        const int sl = r & 1;
        const int i  = r & 7;

        // consume rb[sl] (compiler waits vmcnt only for these 6 regs)
        float y[8];
        y[0] = fmaf(w0, rb[sl][0].x, fmaf(w1, rb[sl][2].x, w2 * rb[sl][4].x));
        y[1] = fmaf(w0, rb[sl][0].y, fmaf(w1, rb[sl][2].y, w2 * rb[sl][4].y));
        y[2] = fmaf(w0, rb[sl][0].z, fmaf(w1, rb[sl][2].z, w2 * rb[sl][4].z));
        y[3] = fmaf(w0, rb[sl][0].w, fmaf(w1, rb[sl][2].w, w2 * rb[sl][4].w));
        y[4] = fmaf(w0, rb[sl][1].x, fmaf(w1, rb[sl][3].x, w2 * rb[sl][5].x));
        y[5] = fmaf(w0, rb[sl][1].y, fmaf(w1, rb[sl][3].y, w2 * rb[sl][5].y));
        y[6] = fmaf(w0, rb[sl][1].z, fmaf(w1, rb[sl][3].z, w2 * rb[sl][5].z));
        y[7] = fmaf(w0, rb[sl][1].w, fmaf(w1, rb[sl][3].w, w2 * rb[sl][5].w));

        // refill the just-consumed slot with row r+2 (keeps 2 rows in flight,
        // including across the band seam: r=6,7 issue rows 8,9 = next band)
        if (r + 2 < 16) issue(sl, r + 2);

        // row-DCT accumulate
#pragma unroll
        for (int u = 0; u < 8; ++u) {
            const float bu = BASIS[u][i];
#pragma unroll
            for (int j = 0; j < 8; ++j)
                tmp[u][j] = fmaf(bu, y[j], tmp[u][j]);
        }

        // band epilogue: col-DCT + norm + stores (never waited on; band n+1
        // row loads are already in flight while this runs)
        if (i == 7) {
            const int by = byp * 2 + (r >> 3);
            float* op = out + ((size_t)obase * 64 + by) * 64 + bx;
#pragma unroll
            for (int u = 0; u < 8; ++u) {
#pragma unroll
                for (int v = 0; v < 8; ++v) {
                    float acc = tmp[u][0] * BASIS[v][0];
#pragma unroll
                    for (int j = 1; j < 8; ++j)
                        acc = fmaf(tmp[u][j], BASIS[v][j], acc);
                    const int k = u * 8 + v;
                    float s, o;
                    if (USE_WS) {
                        s = so[(obase + k) * 2];       // wave-uniform s_load
                        o = so[(obase + k) * 2 + 1];
                    } else {
                        float mn = min_[obase + k], mx = max_[obase + k];
                        float d  = mx - mn + EPS;
                        float a  = 1.0f / d;
                        float a2 = a * a, a4 = a2 * a2, a8 = a4 * a4,
                              a16 = a8 * a8, a32 = a16 * a16;
                        s = a32;
                        o = -mn * (a * (1.0f - a32) / (1.0f - a));
                    }
                    op[(size_t)k * 4096] = fmaf(s, acc, o);  // lanes consecutive
                }
            }
            if (r < 15) {
#pragma unroll
                for (int u = 0; u < 8; ++u)
#pragma unroll
                    for (int j = 0; j < 8; ++j) tmp[u][j] = 0.0f;
            }
        }
    }
}

extern "C" void kernel_launch(void* const* d_in, const int* in_sizes, int n_in,
                              void* d_out, int out_size, void* d_ws, size_t ws_size,
                              hipStream_t stream) {
    const float* x    = (const float*)d_in[0];
    const float* max_ = (const float*)d_in[1];
    const float* min_ = (const float*)d_in[2];
    const float* yw   = (const float*)d_in[3];
    float* out = (float*)d_out;
    float* so  = (float*)d_ws;

    const bool use_ws = (ws_size >= (size_t)NPAIR * 2 * sizeof(float));
    if (use_ws) {
        precomp_norm<<<(NPAIR + 255) / 256, 256, 0, stream>>>(max_, min_, so);
        dct_kernel<true><<<32 * 32, 192, 0, stream>>>(x, yw, so, max_, min_, out);
    } else {
        dct_kernel<false><<<32 * 32, 192, 0, stream>>>(x, yw, nullptr, max_, min_, out);
    }
}